// Round 13
// baseline (388.068 us; speedup 1.0000x reference)
//
#include <hip/hip_runtime.h>
#include <math.h>

#define N_NODES 50000
#define N_EDGES 400000
#define M_PAD 50048
#define NFEAT 512
#define NHID 256
#define NCLASS 8
#define SCAN_BLOCKS ((N_NODES + 255) / 256)   // 196

typedef unsigned short u16;
typedef __attribute__((ext_vector_type(8))) unsigned short u16x8;
typedef __attribute__((ext_vector_type(8))) short s16x8;
typedef __attribute__((ext_vector_type(4))) float f32x4;

__device__ __forceinline__ float bf2f(u16 u) {
    union { unsigned int i; float f; } v; v.i = ((unsigned int)u) << 16; return v.f;
}
__device__ __forceinline__ float bf2f_hi(unsigned int packed) {
    union { unsigned int i; float f; } v; v.i = packed & 0xffff0000u; return v.f;
}
__device__ __forceinline__ float bf2f_lo(unsigned int packed) {
    union { unsigned int i; float f; } v; v.i = packed << 16; return v.f;
}
__device__ __forceinline__ u16 f2bf(float f) {
    union { float f; unsigned int i; } v; v.f = f;
    unsigned int r = v.i + 0x7fffu + ((v.i >> 16) & 1u);
    return (u16)(r >> 16);
}

// ---------------- prep: degrees, CSR ----------------

__global__ void init_k(float* deg, int* cnt, int* cur) {
    int i = blockIdx.x * blockDim.x + threadIdx.x;
    if (i < N_NODES) { deg[i] = 1.0f; cnt[i] = 0; cur[i] = 0; }
}

__global__ void edge_deg_k(const float* __restrict__ p, const int* __restrict__ dst,
                           float* __restrict__ deg, int* __restrict__ cnt,
                           float* __restrict__ ew_out) {
    int e = blockIdx.x * blockDim.x + threadIdx.x;
    if (e >= N_EDGES) return;
    float ew = 1.0f / (1.0f + expf(-p[e]));
    ew_out[e] = ew;
    int d = dst[e];
    atomicAdd(&deg[d], ew);
    atomicAdd(&cnt[d], 1);
}

__global__ void finalize_dinv_k(float* __restrict__ deg, const int* __restrict__ cnt,
                                float* __restrict__ dinv3) {
    int i = blockIdx.x * blockDim.x + threadIdx.x;
    if (i < N_NODES) {
        deg[i]   = 1.0f / sqrtf(deg[i]);
        dinv3[i] = 1.0f / sqrtf(1.0f + (float)cnt[i]);
    }
}

// scan1: per-256-block exclusive scan; bsum[b] = block total.
__global__ __launch_bounds__(256) void scan1_k(const int* __restrict__ cnt,
                                               int* __restrict__ row_start,
                                               int* __restrict__ bsum) {
    __shared__ int tmp[256];
    int t = threadIdx.x;
    int g = blockIdx.x * 256 + t;
    int v = (g < N_NODES) ? cnt[g] : 0;
    tmp[t] = v;
    __syncthreads();
    #pragma unroll
    for (int off = 1; off < 256; off <<= 1) {
        int u = (t >= off) ? tmp[t - off] : 0;
        __syncthreads();
        tmp[t] += u;
        __syncthreads();
    }
    if (g < N_NODES) row_start[g] = tmp[t] - v;
    if (t == 255) bsum[blockIdx.x] = tmp[255];
}

// scan2: exclusive scan of bsum in place; row_start[N_NODES] = last block local total.
__global__ __launch_bounds__(256) void scan2_k(int* __restrict__ bsum,
                                               int* __restrict__ row_start) {
    __shared__ int tmp[256];
    int t = threadIdx.x;
    int v = (t < SCAN_BLOCKS) ? bsum[t] : 0;
    tmp[t] = v;
    __syncthreads();
    #pragma unroll
    for (int off = 1; off < 256; off <<= 1) {
        int u = (t >= off) ? tmp[t - off] : 0;
        __syncthreads();
        tmp[t] += u;
        __syncthreads();
    }
    if (t < SCAN_BLOCKS) bsum[t] = tmp[t] - v;
    if (t == SCAN_BLOCKS - 1) row_start[N_NODES] = v;
}

__global__ void fill_k(const int* __restrict__ src, const int* __restrict__ dst,
                       const float* __restrict__ ew, const float* __restrict__ dinv,
                       const float* __restrict__ dinv3,
                       const int* __restrict__ row_start, const int* __restrict__ bsum,
                       int* __restrict__ cur,
                       uint2* __restrict__ ep, uint2* __restrict__ ep3) {
    int e = blockIdx.x * blockDim.x + threadIdx.x;
    if (e >= N_EDGES) return;
    int s = src[e], d = dst[e];
    float w  = dinv[s] * ew[e] * dinv[d];
    float w3 = dinv3[s] * dinv3[d];
    int p = atomicAdd(&cur[d], 1);
    int slot = row_start[d] + bsum[d >> 8] + p;
    ep[slot]  = make_uint2((unsigned int)s, __float_as_uint(w));
    ep3[slot] = make_uint2((unsigned int)s, __float_as_uint(w3));
}

// ---------------- weight transpose + zeropad (merged) ----------------

#define WT_TOTAL (256 * 512 + 2 * 256 * 256)
#define ZP_TOTAL ((M_PAD - N_NODES) * 256)

__global__ void wtrans_zp_k(const float* __restrict__ W1, const float* __restrict__ W2,
                            const float* __restrict__ W3, u16* __restrict__ wt1,
                            u16* __restrict__ wt2, u16* __restrict__ wt3,
                            u16* __restrict__ zp_a, u16* __restrict__ zp_b) {
    int idx = blockIdx.x * 256 + threadIdx.x;
    if (idx < WT_TOTAL) {
        const float* W; u16* Wt; int K;
        if (idx < 256 * 512)                  { W = W1; Wt = wt1; K = 512; }
        else if (idx < 256 * 512 + 256 * 256) { idx -= 256 * 512; W = W2; Wt = wt2; K = 256; }
        else                                  { idx -= 256 * 512 + 256 * 256; W = W3; Wt = wt3; K = 256; }
        int n = idx / K, k = idx - n * K;
        Wt[(size_t)n * K + k] = f2bf(W[(size_t)k * 256 + n]);
        return;
    }
    int z = idx - WT_TOTAL;
    if (z < ZP_TOTAL) {
        zp_a[(size_t)N_NODES * 256 + z] = 0;
        zp_b[(size_t)N_NODES * 256 + z] = 0;
    }
}

// ---------------- B-panel-resident barrier-free GEMM ----------------
// C[M_PAD x 256] = A[M_PAD x K] @ BT[256 x K]^T.
// Block owns 64 output cols; stages BT panel into LDS ONCE (XOR-swizzled:
// element offset ^= (col&7)<<3, byte bits 4-6 -> 8 bank phases, 2 lanes/phase
// = free), one barrier, then each of 4 waves independently grid-strides over
// 128-row panels (wave = 32 rows x 64 cols), streaming A to registers.
// NO barriers in the K loop; all hazards wave-local counted waitcnt.
// READ SIDE uses the FULL XOR on the complete element offset per step
// (r12 bug: T*32 + (kg^sw) != (T*32+kg)^sw when sw has bit 5 set — carry vs flip).
// AF32: layer-1 A is fp32, converted in registers (pad rows read as 0).

__device__ __forceinline__ u16x8 ldcvt_f32(const float* p, bool ok) {
    u16x8 o = {0, 0, 0, 0, 0, 0, 0, 0};
    if (ok) {
        float4 a = *(const float4*)p;
        float4 b = *(const float4*)(p + 4);
        o[0] = f2bf(a.x); o[1] = f2bf(a.y); o[2] = f2bf(a.z); o[3] = f2bf(a.w);
        o[4] = f2bf(b.x); o[5] = f2bf(b.y); o[6] = f2bf(b.z); o[7] = f2bf(b.w);
    }
    return o;
}

#define LOADA(AV, T)                                                            \
    do {                                                                        \
        _Pragma("unroll")                                                       \
        for (int m = 0; m < 2; ++m) {                                           \
            if constexpr (AF32) AV[m] = (s16x8)ldcvt_f32(ap32[m] + (T) * 32, ok[m]); \
            else                AV[m] = *(const s16x8*)(ap16[m] + (T) * 32);    \
        }                                                                       \
    } while (0)

#define BSTEP(AV, T)                                                            \
    do {                                                                        \
        int ko = ((T) * 32 + kg) ^ sw;     /* full-offset XOR: exact inverse */ \
        s16x8 bf[4];                                                            \
        _Pragma("unroll")                                                       \
        for (int n = 0; n < 4; ++n)                                             \
            bf[n] = *(const s16x8*)&Bsl[(n * 16 + fr) * K + ko];                \
        _Pragma("unroll")                                                       \
        for (int m = 0; m < 2; ++m)                                             \
            _Pragma("unroll")                                                   \
            for (int n = 0; n < 4; ++n)                                         \
                acc[m][n] = __builtin_amdgcn_mfma_f32_16x16x32_bf16(AV[m], bf[n], acc[m][n], 0, 0, 0); \
    } while (0)

template <bool AF32, int K>
__global__ __launch_bounds__(256) void gemm_bp_k(const void* __restrict__ Ap,
                                                 const u16* __restrict__ BT,
                                                 u16* __restrict__ C, int GY) {
    __shared__ u16 Bsl[64 * K];     // 64 KB (K=512) / 32 KB (K=256)
    int tid = threadIdx.x, lane = tid & 63, wid = tid >> 6;
    int colbase = blockIdx.x * 64;
    const int kchunks = K >> 3;

    // stage B panel: element chunk kc of col stored at kc ^ ((col&7)<<3)
    for (int i = tid; i < 64 * kchunks; i += 256) {
        int col = i / kchunks;
        int kc = (i - col * kchunks) << 3;
        *(u16x8*)&Bsl[col * K + (kc ^ ((col & 7) << 3))] =
            *(const u16x8*)&BT[(size_t)(colbase + col) * K + kc];
    }
    __syncthreads();                // the only block barrier

    int fr = lane & 15;
    int kg = (lane >> 4) << 3;
    int sw = (fr & 7) << 3;         // (n*16+fr)&7 == fr&7 for all n
    const u16*   A16 = (const u16*)Ap;
    const float* A32 = (const float*)Ap;
    const int nt = K >> 5;          // even (16 or 8)

    for (int p = blockIdx.y; p < M_PAD / 128; p += GY) {
        int row0 = p * 128 + wid * 32;
        const u16* ap16[2]; const float* ap32[2]; bool ok[2];
        #pragma unroll
        for (int m = 0; m < 2; ++m) {
            int gr = row0 + m * 16 + fr;
            ok[m]   = gr < N_NODES;
            ap16[m] = A16 + (size_t)gr * K + kg;
            ap32[m] = A32 + (size_t)gr * K + kg;
        }
        f32x4 acc[2][4] = {};
        s16x8 aa[2], ab[2];
        LOADA(aa, 0);
        #pragma unroll
        for (int t = 0; t < nt; t += 2) {
            LOADA(ab, t + 1);
            BSTEP(aa, t);
            if (t + 2 < nt) LOADA(aa, t + 2);
            BSTEP(ab, t + 1);
        }
        // C/D layout: col = lane&15, row = (lane>>4)*4 + r
        int crow0 = row0 + ((lane >> 4) << 2);
        int ccol  = colbase + fr;
        #pragma unroll
        for (int m = 0; m < 2; ++m)
            #pragma unroll
            for (int n = 0; n < 4; ++n)
                #pragma unroll
                for (int r = 0; r < 4; ++r)
                    C[(size_t)(crow0 + m * 16 + r) * 256 + ccol + n * 16] = f2bf(acc[m][n][r]);
    }
}

// ---------------- gather (bf16 in/out), edge loop unrolled x8/x4/x1 ----------------

__device__ __forceinline__ void fma4(float4& acc, uint2 u, float w) {
    acc.x += bf2f_lo(u.x) * w; acc.y += bf2f_hi(u.x) * w;
    acc.z += bf2f_lo(u.y) * w; acc.w += bf2f_hi(u.y) * w;
}

template <bool RELU>
__global__ __launch_bounds__(256) void gather_k(const u16* __restrict__ h,
                                                const int* __restrict__ row_start,
                                                const int* __restrict__ bsum,
                                                const uint2* __restrict__ ep,
                                                const float* __restrict__ dinv,
                                                const float* __restrict__ bias,
                                                u16* __restrict__ outb) {
    int node = blockIdx.x * 4 + (threadIdx.x >> 6);
    if (node >= N_NODES) return;
    int lane = threadIdx.x & 63;

    float di = dinv[node];
    float sw = di * di;
    uint2 hv = *(const uint2*)(h + (size_t)node * 256 + lane * 4);
    float4 acc;
    acc.x = bf2f_lo(hv.x) * sw; acc.y = bf2f_hi(hv.x) * sw;
    acc.z = bf2f_lo(hv.y) * sw; acc.w = bf2f_hi(hv.y) * sw;

    int beg = row_start[node] + bsum[node >> 8];
    int end = row_start[node + 1] + bsum[(node + 1) >> 8];
    int j = beg;
    for (; j + 8 <= end; j += 8) {
        uint2 e0 = ep[j],     e1 = ep[j + 1], e2 = ep[j + 2], e3 = ep[j + 3];
        uint2 e4 = ep[j + 4], e5 = ep[j + 5], e6 = ep[j + 6], e7 = ep[j + 7];
        uint2 u0 = *(const uint2*)(h + (size_t)e0.x * 256 + lane * 4);
        uint2 u1 = *(const uint2*)(h + (size_t)e1.x * 256 + lane * 4);
        uint2 u2 = *(const uint2*)(h + (size_t)e2.x * 256 + lane * 4);
        uint2 u3 = *(const uint2*)(h + (size_t)e3.x * 256 + lane * 4);
        uint2 u4 = *(const uint2*)(h + (size_t)e4.x * 256 + lane * 4);
        uint2 u5 = *(const uint2*)(h + (size_t)e5.x * 256 + lane * 4);
        uint2 u6 = *(const uint2*)(h + (size_t)e6.x * 256 + lane * 4);
        uint2 u7 = *(const uint2*)(h + (size_t)e7.x * 256 + lane * 4);
        fma4(acc, u0, __uint_as_float(e0.y)); fma4(acc, u1, __uint_as_float(e1.y));
        fma4(acc, u2, __uint_as_float(e2.y)); fma4(acc, u3, __uint_as_float(e3.y));
        fma4(acc, u4, __uint_as_float(e4.y)); fma4(acc, u5, __uint_as_float(e5.y));
        fma4(acc, u6, __uint_as_float(e6.y)); fma4(acc, u7, __uint_as_float(e7.y));
    }
    for (; j + 4 <= end; j += 4) {
        uint2 e0 = ep[j], e1 = ep[j + 1], e2 = ep[j + 2], e3 = ep[j + 3];
        uint2 u0 = *(const uint2*)(h + (size_t)e0.x * 256 + lane * 4);
        uint2 u1 = *(const uint2*)(h + (size_t)e1.x * 256 + lane * 4);
        uint2 u2 = *(const uint2*)(h + (size_t)e2.x * 256 + lane * 4);
        uint2 u3 = *(const uint2*)(h + (size_t)e3.x * 256 + lane * 4);
        fma4(acc, u0, __uint_as_float(e0.y)); fma4(acc, u1, __uint_as_float(e1.y));
        fma4(acc, u2, __uint_as_float(e2.y)); fma4(acc, u3, __uint_as_float(e3.y));
    }
    for (; j < end; ++j) {
        uint2 e = ep[j];
        uint2 u = *(const uint2*)(h + (size_t)e.x * 256 + lane * 4);
        fma4(acc, u, __uint_as_float(e.y));
    }
    float4 bv = ((const float4*)bias)[lane];
    acc.x += bv.x; acc.y += bv.y; acc.z += bv.z; acc.w += bv.w;
    if (RELU) {
        acc.x = fmaxf(acc.x, 0.f); acc.y = fmaxf(acc.y, 0.f);
        acc.z = fmaxf(acc.z, 0.f); acc.w = fmaxf(acc.w, 0.f);
    }
    uint2 o;
    o.x = (unsigned int)f2bf(acc.x) | ((unsigned int)f2bf(acc.y) << 16);
    o.y = (unsigned int)f2bf(acc.z) | ((unsigned int)f2bf(acc.w) << 16);
    *(uint2*)(outb + (size_t)node * 256 + lane * 4) = o;
}

// ---------------- final linear (+ fused log_softmax on last segment) ----------------

template <int MODE>
__global__ __launch_bounds__(256) void logits_acc_k(const u16* __restrict__ x,
                                                    const float* __restrict__ Wlin,
                                                    const float* __restrict__ blin,
                                                    float* __restrict__ logits,
                                                    float* __restrict__ out, int seg) {
    __shared__ float Ws[256 * 8];
    int tid = threadIdx.x;
    const float* Wseg = Wlin + (size_t)seg * 256 * 8;
    for (int i = tid; i < 2048; i += 256) Ws[i] = Wseg[i];
    __syncthreads();
    int row = blockIdx.x * 32 + (tid >> 3);
    int c = tid & 7;
    if (row >= N_NODES) return;
    const u16* xr = x + (size_t)row * 256;
    float acc = 0.f;
    for (int k8 = 0; k8 < 32; ++k8) {
        u16x8 v = *(const u16x8*)&xr[k8 * 8];
        #pragma unroll
        for (int i = 0; i < 8; ++i) acc += bf2f(v[i]) * Ws[(k8 * 8 + i) * 8 + c];
    }
    float* lp = &logits[(size_t)row * 8 + c];
    if (MODE == 0) {
        *lp = acc + blin[c];
    } else if (MODE == 1) {
        *lp += acc;
    } else {
        float t = *lp + acc;
        float m = t;
        m = fmaxf(m, __shfl_xor(m, 1));
        m = fmaxf(m, __shfl_xor(m, 2));
        m = fmaxf(m, __shfl_xor(m, 4));
        float s = expf(t - m);
        s += __shfl_xor(s, 1);
        s += __shfl_xor(s, 2);
        s += __shfl_xor(s, 4);
        out[(size_t)row * 8 + c] = t - (logf(s) + m);
    }
}

// ---------------- driver ----------------

extern "C" void kernel_launch(void* const* d_in, const int* in_sizes, int n_in,
                              void* d_out, int out_size, void* d_ws, size_t ws_size,
                              hipStream_t stream) {
    const float* x    = (const float*)d_in[0];
    const int*   ei   = (const int*)d_in[1];
    const float* ewp  = (const float*)d_in[2];
    const float* W1   = (const float*)d_in[3];
    const float* b1   = (const float*)d_in[4];
    const float* W2   = (const float*)d_in[5];
    const float* b2   = (const float*)d_in[6];
    const float* W3   = (const float*)d_in[7];
    const float* b3   = (const float*)d_in[8];
    const float* Wlin = (const float*)d_in[9];
    const float* blin = (const float*)d_in[10];
    float* out = (float*)d_out;

    const int* src = ei;
    const int* dst = ei + N_EDGES;

    float* ws = (float*)d_ws;
    float* ew     = ws;                                  // E
    float* dinv   = ew + N_EDGES;                        // N
    float* dinv3  = dinv + N_NODES;                      // N
    float* logits = dinv3 + N_NODES;                     // N*8
    int* cnt       = (int*)(logits + (size_t)N_NODES * 8);
    int* cur       = cnt + N_NODES;
    int* row_start = cur + N_NODES;                      // N+1 (block-local)
    int* bsum      = row_start + N_NODES + 1;            // SCAN_BLOCKS
    uint2* ep  = (uint2*)(((uintptr_t)(bsum + SCAN_BLOCKS) + 127) & ~(uintptr_t)127);  // E
    uint2* ep3 = ep + N_EDGES;                           // E
    u16* hb  = (u16*)(ep3 + N_EDGES);                    // M_PAD*256
    u16* x1b = hb  + (size_t)M_PAD * 256;
    u16* x2b = x1b + (size_t)M_PAD * 256;
    u16* x3b = x2b + (size_t)M_PAD * 256;
    u16* wt1 = x3b + (size_t)M_PAD * 256;                // 256*512
    u16* wt2 = wt1 + 256 * 512;
    u16* wt3 = wt2 + 256 * 256;

    dim3 blk(256);
    int nodeBlocks  = (N_NODES + 255) / 256;
    int edgeBlocks  = (N_EDGES + 255) / 256;
    int gathBlocks  = (N_NODES + 3) / 4;
    int rowBlocks32 = (N_NODES + 31) / 32;

    // prep + CSR
    init_k<<<nodeBlocks, blk, 0, stream>>>(dinv, cnt, cur);
    edge_deg_k<<<edgeBlocks, blk, 0, stream>>>(ewp, dst, dinv, cnt, ew);
    finalize_dinv_k<<<nodeBlocks, blk, 0, stream>>>(dinv, cnt, dinv3);
    scan1_k<<<SCAN_BLOCKS, blk, 0, stream>>>(cnt, row_start, bsum);
    scan2_k<<<1, blk, 0, stream>>>(bsum, row_start);
    fill_k<<<edgeBlocks, blk, 0, stream>>>(src, dst, ew, dinv, dinv3, row_start, bsum,
                                           cur, ep, ep3);

    // weights + pads (merged)
    wtrans_zp_k<<<(WT_TOTAL + ZP_TOTAL + 255) / 256, blk, 0, stream>>>(
        W1, W2, W3, wt1, wt2, wt3, x1b, x2b);

    // ---- layer 1 (A = fp32 x, converted in registers)
    gemm_bp_k<true, 512><<<dim3(4, 128), blk, 0, stream>>>(x, wt1, hb, 128);
    gather_k<true><<<gathBlocks, blk, 0, stream>>>(hb, row_start, bsum, ep, dinv, b1, x1b);
    logits_acc_k<0><<<rowBlocks32, blk, 0, stream>>>(x1b, Wlin, blin, logits, nullptr, 0);

    // ---- layer 2
    gemm_bp_k<false, 256><<<dim3(4, 256), blk, 0, stream>>>(x1b, wt2, hb, 256);
    gather_k<true><<<gathBlocks, blk, 0, stream>>>(hb, row_start, bsum, ep, dinv, b2, x2b);
    logits_acc_k<1><<<rowBlocks32, blk, 0, stream>>>(x2b, Wlin, blin, logits, nullptr, 1);

    // ---- layer 3 (ones edge weights) + fused log_softmax in the logits pass
    gemm_bp_k<false, 256><<<dim3(4, 256), blk, 0, stream>>>(x2b, wt3, hb, 256);
    gather_k<false><<<gathBlocks, blk, 0, stream>>>(hb, row_start, bsum, ep3, dinv3, b3, x3b);
    logits_acc_k<2><<<rowBlocks32, blk, 0, stream>>>(x3b, Wlin, blin, logits, out, 2);
}

// Round 14
// 310.226 us; speedup vs baseline: 1.2509x; 1.2509x over previous
//
#include <hip/hip_runtime.h>
#include <math.h>

#define N_NODES 50000
#define N_EDGES 400000
#define M_PAD 50048
#define NFEAT 512
#define NHID 256
#define NCLASS 8
#define SCAN_BLOCKS ((N_NODES + 255) / 256)   // 196

typedef unsigned short u16;
typedef __attribute__((ext_vector_type(8))) unsigned short u16x8;
typedef __attribute__((ext_vector_type(8))) short s16x8;
typedef __attribute__((ext_vector_type(4))) float f32x4;

__device__ __forceinline__ float bf2f(u16 u) {
    union { unsigned int i; float f; } v; v.i = ((unsigned int)u) << 16; return v.f;
}
__device__ __forceinline__ float bf2f_hi(unsigned int packed) {
    union { unsigned int i; float f; } v; v.i = packed & 0xffff0000u; return v.f;
}
__device__ __forceinline__ float bf2f_lo(unsigned int packed) {
    union { unsigned int i; float f; } v; v.i = packed << 16; return v.f;
}
__device__ __forceinline__ u16 f2bf(float f) {
    union { float f; unsigned int i; } v; v.f = f;
    unsigned int r = v.i + 0x7fffu + ((v.i >> 16) & 1u);
    return (u16)(r >> 16);
}

// ---------------- prep: degrees, CSR ----------------

__global__ void init_k(float* deg, int* cnt, int* cur) {
    int i = blockIdx.x * blockDim.x + threadIdx.x;
    if (i < N_NODES) { deg[i] = 1.0f; cnt[i] = 0; cur[i] = 0; }
}

__global__ void edge_deg_k(const float* __restrict__ p, const int* __restrict__ dst,
                           float* __restrict__ deg, int* __restrict__ cnt,
                           float* __restrict__ ew_out) {
    int e = blockIdx.x * blockDim.x + threadIdx.x;
    if (e >= N_EDGES) return;
    float ew = 1.0f / (1.0f + expf(-p[e]));
    ew_out[e] = ew;
    int d = dst[e];
    atomicAdd(&deg[d], ew);
    atomicAdd(&cnt[d], 1);
}

__global__ void finalize_dinv_k(float* __restrict__ deg, const int* __restrict__ cnt,
                                float* __restrict__ dinv3) {
    int i = blockIdx.x * blockDim.x + threadIdx.x;
    if (i < N_NODES) {
        deg[i]   = 1.0f / sqrtf(deg[i]);
        dinv3[i] = 1.0f / sqrtf(1.0f + (float)cnt[i]);
    }
}

// scan1: per-256-block exclusive scan; bsum[b] = block total.
__global__ __launch_bounds__(256) void scan1_k(const int* __restrict__ cnt,
                                               int* __restrict__ row_start,
                                               int* __restrict__ bsum) {
    __shared__ int tmp[256];
    int t = threadIdx.x;
    int g = blockIdx.x * 256 + t;
    int v = (g < N_NODES) ? cnt[g] : 0;
    tmp[t] = v;
    __syncthreads();
    #pragma unroll
    for (int off = 1; off < 256; off <<= 1) {
        int u = (t >= off) ? tmp[t - off] : 0;
        __syncthreads();
        tmp[t] += u;
        __syncthreads();
    }
    if (g < N_NODES) row_start[g] = tmp[t] - v;
    if (t == 255) bsum[blockIdx.x] = tmp[255];
}

// scan2: exclusive scan of bsum in place; row_start[N_NODES] = last block local total.
__global__ __launch_bounds__(256) void scan2_k(int* __restrict__ bsum,
                                               int* __restrict__ row_start) {
    __shared__ int tmp[256];
    int t = threadIdx.x;
    int v = (t < SCAN_BLOCKS) ? bsum[t] : 0;
    tmp[t] = v;
    __syncthreads();
    #pragma unroll
    for (int off = 1; off < 256; off <<= 1) {
        int u = (t >= off) ? tmp[t - off] : 0;
        __syncthreads();
        tmp[t] += u;
        __syncthreads();
    }
    if (t < SCAN_BLOCKS) bsum[t] = tmp[t] - v;
    if (t == SCAN_BLOCKS - 1) row_start[N_NODES] = v;
}

__global__ void fill_k(const int* __restrict__ src, const int* __restrict__ dst,
                       const float* __restrict__ ew, const float* __restrict__ dinv,
                       const float* __restrict__ dinv3,
                       const int* __restrict__ row_start, const int* __restrict__ bsum,
                       int* __restrict__ cur,
                       uint2* __restrict__ ep, uint2* __restrict__ ep3) {
    int e = blockIdx.x * blockDim.x + threadIdx.x;
    if (e >= N_EDGES) return;
    int s = src[e], d = dst[e];
    float w  = dinv[s] * ew[e] * dinv[d];
    float w3 = dinv3[s] * dinv3[d];
    int p = atomicAdd(&cur[d], 1);
    int slot = row_start[d] + bsum[d >> 8] + p;
    ep[slot]  = make_uint2((unsigned int)s, __float_as_uint(w));
    ep3[slot] = make_uint2((unsigned int)s, __float_as_uint(w3));
}

// ---------------- weight transpose + zeropad (merged) ----------------

#define WT_TOTAL (256 * 512 + 2 * 256 * 256)
#define ZP_TOTAL ((M_PAD - N_NODES) * 256)

__global__ void wtrans_zp_k(const float* __restrict__ W1, const float* __restrict__ W2,
                            const float* __restrict__ W3, u16* __restrict__ wt1,
                            u16* __restrict__ wt2, u16* __restrict__ wt3,
                            u16* __restrict__ zp_a, u16* __restrict__ zp_b) {
    int idx = blockIdx.x * 256 + threadIdx.x;
    if (idx < WT_TOTAL) {
        const float* W; u16* Wt; int K;
        if (idx < 256 * 512)                  { W = W1; Wt = wt1; K = 512; }
        else if (idx < 256 * 512 + 256 * 256) { idx -= 256 * 512; W = W2; Wt = wt2; K = 256; }
        else                                  { idx -= 256 * 512 + 256 * 256; W = W3; Wt = wt3; K = 256; }
        int n = idx / K, k = idx - n * K;
        Wt[(size_t)n * K + k] = f2bf(W[(size_t)k * 256 + n]);
        return;
    }
    int z = idx - WT_TOTAL;
    if (z < ZP_TOTAL) {
        zp_a[(size_t)N_NODES * 256 + z] = 0;
        zp_b[(size_t)N_NODES * 256 + z] = 0;
    }
}

// ---------------- bf16 MFMA GEMM (r11 structure + depth-2 register prefetch) ----------------
// C[M_PAD x 256] = A[M_PAD x K] @ BT[256 x K]^T. 128x128 tile, BK=32, 4 waves,
// padded-40 LDS rows. Two named register sets P/Q: at step t we issue loads for
// t+2, so each load gets ~2 compute phases of latency cover (r11 had 1).
// AF32: layer-1 A is fp32, converted in registers (pad rows read as 0).

__device__ __forceinline__ u16x8 ldcvt_f32(const float* p, bool ok) {
    u16x8 o = {0, 0, 0, 0, 0, 0, 0, 0};
    if (ok) {
        float4 a = *(const float4*)p;
        float4 b = *(const float4*)(p + 4);
        o[0] = f2bf(a.x); o[1] = f2bf(a.y); o[2] = f2bf(a.z); o[3] = f2bf(a.w);
        o[4] = f2bf(b.x); o[5] = f2bf(b.y); o[6] = f2bf(b.z); o[7] = f2bf(b.w);
    }
    return o;
}

#define GLOAD(A0, A1, B0, B1, KO)                                               \
    do {                                                                        \
        if (AF32) { A0 = ldcvt_f32(Af0 + (KO), ok0); A1 = ldcvt_f32(Af1 + (KO), ok1); } \
        else      { A0 = *(const u16x8*)(Ag0 + (KO)); A1 = *(const u16x8*)(Ag1 + (KO)); } \
        B0 = *(const u16x8*)(Bg0 + (KO));                                       \
        B1 = *(const u16x8*)(Bg1 + (KO));                                       \
    } while (0)

#define LDSWRITE(A0, A1, B0, B1)                                                \
    do {                                                                        \
        *(u16x8*)&Asl[la0] = A0; *(u16x8*)&Asl[la1] = A1;                       \
        *(u16x8*)&Bsl[la0] = B0; *(u16x8*)&Bsl[la1] = B1;                       \
    } while (0)

#define COMPUTE()                                                               \
    do {                                                                        \
        s16x8 af[4], bf[4];                                                     \
        _Pragma("unroll")                                                       \
        for (int m = 0; m < 4; ++m)                                             \
            af[m] = *(const s16x8*)&Asl[(arow + m * 16) * 40 + kg];             \
        _Pragma("unroll")                                                       \
        for (int n = 0; n < 4; ++n)                                             \
            bf[n] = *(const s16x8*)&Bsl[(bcol + n * 16) * 40 + kg];             \
        _Pragma("unroll")                                                       \
        for (int m = 0; m < 4; ++m)                                             \
            _Pragma("unroll")                                                   \
            for (int n = 0; n < 4; ++n)                                         \
                acc[m][n] = __builtin_amdgcn_mfma_f32_16x16x32_bf16(af[m], bf[n], acc[m][n], 0, 0, 0); \
    } while (0)

template <bool AF32>
__global__ __launch_bounds__(256) void gemm_bf16_k(const void* __restrict__ Ap,
                                                   const u16* __restrict__ BT,
                                                   u16* __restrict__ C, int K) {
    __shared__ u16 Asl[128 * 40];
    __shared__ u16 Bsl[128 * 40];
    int tid = threadIdx.x;
    int lane = tid & 63;
    int wid = tid >> 6;
    int wm = wid >> 1, wn = wid & 1;
    int row0 = blockIdx.x * 128;
    int col0 = blockIdx.y * 128;

    int c0 = tid, c1 = tid + 256;
    int ar0 = c0 >> 2, ak0 = (c0 & 3) << 3;
    int ar1 = c1 >> 2, ak1 = (c1 & 3) << 3;
    const u16*   A16 = (const u16*)Ap;
    const float* A32 = (const float*)Ap;
    bool ok0 = (row0 + ar0) < N_NODES;
    bool ok1 = (row0 + ar1) < N_NODES;
    const u16* Ag0 = A16 + (size_t)(row0 + ar0) * K + ak0;
    const u16* Ag1 = A16 + (size_t)(row0 + ar1) * K + ak1;
    const float* Af0 = A32 + (size_t)(row0 + ar0) * K + ak0;
    const float* Af1 = A32 + (size_t)(row0 + ar1) * K + ak1;
    const u16* Bg0 = BT + (size_t)(col0 + ar0) * K + ak0;
    const u16* Bg1 = BT + (size_t)(col0 + ar1) * K + ak1;
    int la0 = ar0 * 40 + ak0, la1 = ar1 * 40 + ak1;

    u16x8 pa0, pa1, pb0, pb1;     // set P (even steps)
    u16x8 qa0, qa1, qb0, qb1;     // set Q (odd steps)
    GLOAD(pa0, pa1, pb0, pb1, 0);
    GLOAD(qa0, qa1, qb0, qb1, 32);   // nt >= 8 always

    f32x4 acc[4][4] = {};
    int arow = wm * 64 + (lane & 15);
    int bcol = wn * 64 + (lane & 15);
    int kg = (lane >> 4) << 3;

    int nt = K >> 5;                 // even (16 or 8)
    for (int t = 0; t < nt; t += 2) {
        __syncthreads();
        LDSWRITE(pa0, pa1, pb0, pb1);            // step t data
        __syncthreads();
        if (t + 2 < nt) GLOAD(pa0, pa1, pb0, pb1, (t + 2) << 5);
        COMPUTE();                               // step t
        __syncthreads();
        LDSWRITE(qa0, qa1, qb0, qb1);            // step t+1 data
        __syncthreads();
        if (t + 3 < nt) GLOAD(qa0, qa1, qb0, qb1, (t + 3) << 5);
        COMPUTE();                               // step t+1
    }

    // C/D layout: col = lane&15, row = (lane>>4)*4 + r
    int crow0 = row0 + wm * 64 + ((lane >> 4) << 2);
    int ccol  = col0 + wn * 64 + (lane & 15);
    #pragma unroll
    for (int m = 0; m < 4; ++m)
        #pragma unroll
        for (int n = 0; n < 4; ++n)
            #pragma unroll
            for (int r = 0; r < 4; ++r)
                C[(size_t)(crow0 + m * 16 + r) * 256 + ccol + n * 16] = f2bf(acc[m][n][r]);
}

// ---------------- gather (bf16 in/out), edge loop unrolled x8/x4/x1 ----------------

__device__ __forceinline__ void fma4(float4& acc, uint2 u, float w) {
    acc.x += bf2f_lo(u.x) * w; acc.y += bf2f_hi(u.x) * w;
    acc.z += bf2f_lo(u.y) * w; acc.w += bf2f_hi(u.y) * w;
}

template <bool RELU>
__global__ __launch_bounds__(256) void gather_k(const u16* __restrict__ h,
                                                const int* __restrict__ row_start,
                                                const int* __restrict__ bsum,
                                                const uint2* __restrict__ ep,
                                                const float* __restrict__ dinv,
                                                const float* __restrict__ bias,
                                                u16* __restrict__ outb) {
    int node = blockIdx.x * 4 + (threadIdx.x >> 6);
    if (node >= N_NODES) return;
    int lane = threadIdx.x & 63;

    float di = dinv[node];
    float sw = di * di;
    uint2 hv = *(const uint2*)(h + (size_t)node * 256 + lane * 4);
    float4 acc;
    acc.x = bf2f_lo(hv.x) * sw; acc.y = bf2f_hi(hv.x) * sw;
    acc.z = bf2f_lo(hv.y) * sw; acc.w = bf2f_hi(hv.y) * sw;

    int beg = row_start[node] + bsum[node >> 8];
    int end = row_start[node + 1] + bsum[(node + 1) >> 8];
    int j = beg;
    for (; j + 8 <= end; j += 8) {
        uint2 e0 = ep[j],     e1 = ep[j + 1], e2 = ep[j + 2], e3 = ep[j + 3];
        uint2 e4 = ep[j + 4], e5 = ep[j + 5], e6 = ep[j + 6], e7 = ep[j + 7];
        uint2 u0 = *(const uint2*)(h + (size_t)e0.x * 256 + lane * 4);
        uint2 u1 = *(const uint2*)(h + (size_t)e1.x * 256 + lane * 4);
        uint2 u2 = *(const uint2*)(h + (size_t)e2.x * 256 + lane * 4);
        uint2 u3 = *(const uint2*)(h + (size_t)e3.x * 256 + lane * 4);
        uint2 u4 = *(const uint2*)(h + (size_t)e4.x * 256 + lane * 4);
        uint2 u5 = *(const uint2*)(h + (size_t)e5.x * 256 + lane * 4);
        uint2 u6 = *(const uint2*)(h + (size_t)e6.x * 256 + lane * 4);
        uint2 u7 = *(const uint2*)(h + (size_t)e7.x * 256 + lane * 4);
        fma4(acc, u0, __uint_as_float(e0.y)); fma4(acc, u1, __uint_as_float(e1.y));
        fma4(acc, u2, __uint_as_float(e2.y)); fma4(acc, u3, __uint_as_float(e3.y));
        fma4(acc, u4, __uint_as_float(e4.y)); fma4(acc, u5, __uint_as_float(e5.y));
        fma4(acc, u6, __uint_as_float(e6.y)); fma4(acc, u7, __uint_as_float(e7.y));
    }
    for (; j + 4 <= end; j += 4) {
        uint2 e0 = ep[j], e1 = ep[j + 1], e2 = ep[j + 2], e3 = ep[j + 3];
        uint2 u0 = *(const uint2*)(h + (size_t)e0.x * 256 + lane * 4);
        uint2 u1 = *(const uint2*)(h + (size_t)e1.x * 256 + lane * 4);
        uint2 u2 = *(const uint2*)(h + (size_t)e2.x * 256 + lane * 4);
        uint2 u3 = *(const uint2*)(h + (size_t)e3.x * 256 + lane * 4);
        fma4(acc, u0, __uint_as_float(e0.y)); fma4(acc, u1, __uint_as_float(e1.y));
        fma4(acc, u2, __uint_as_float(e2.y)); fma4(acc, u3, __uint_as_float(e3.y));
    }
    for (; j < end; ++j) {
        uint2 e = ep[j];
        uint2 u = *(const uint2*)(h + (size_t)e.x * 256 + lane * 4);
        fma4(acc, u, __uint_as_float(e.y));
    }
    float4 bv = ((const float4*)bias)[lane];
    acc.x += bv.x; acc.y += bv.y; acc.z += bv.z; acc.w += bv.w;
    if (RELU) {
        acc.x = fmaxf(acc.x, 0.f); acc.y = fmaxf(acc.y, 0.f);
        acc.z = fmaxf(acc.z, 0.f); acc.w = fmaxf(acc.w, 0.f);
    }
    uint2 o;
    o.x = (unsigned int)f2bf(acc.x) | ((unsigned int)f2bf(acc.y) << 16);
    o.y = (unsigned int)f2bf(acc.z) | ((unsigned int)f2bf(acc.w) << 16);
    *(uint2*)(outb + (size_t)node * 256 + lane * 4) = o;
}

// ---------------- final linear (+ fused log_softmax on last segment) ----------------

template <int MODE>
__global__ __launch_bounds__(256) void logits_acc_k(const u16* __restrict__ x,
                                                    const float* __restrict__ Wlin,
                                                    const float* __restrict__ blin,
                                                    float* __restrict__ logits,
                                                    float* __restrict__ out, int seg) {
    __shared__ float Ws[256 * 8];
    int tid = threadIdx.x;
    const float* Wseg = Wlin + (size_t)seg * 256 * 8;
    for (int i = tid; i < 2048; i += 256) Ws[i] = Wseg[i];
    __syncthreads();
    int row = blockIdx.x * 32 + (tid >> 3);
    int c = tid & 7;
    if (row >= N_NODES) return;
    const u16* xr = x + (size_t)row * 256;
    float acc = 0.f;
    for (int k8 = 0; k8 < 32; ++k8) {
        u16x8 v = *(const u16x8*)&xr[k8 * 8];
        #pragma unroll
        for (int i = 0; i < 8; ++i) acc += bf2f(v[i]) * Ws[(k8 * 8 + i) * 8 + c];
    }
    float* lp = &logits[(size_t)row * 8 + c];
    if (MODE == 0) {
        *lp = acc + blin[c];
    } else if (MODE == 1) {
        *lp += acc;
    } else {
        float t = *lp + acc;
        float m = t;
        m = fmaxf(m, __shfl_xor(m, 1));
        m = fmaxf(m, __shfl_xor(m, 2));
        m = fmaxf(m, __shfl_xor(m, 4));
        float s = expf(t - m);
        s += __shfl_xor(s, 1);
        s += __shfl_xor(s, 2);
        s += __shfl_xor(s, 4);
        out[(size_t)row * 8 + c] = t - (logf(s) + m);
    }
}

// ---------------- driver ----------------

extern "C" void kernel_launch(void* const* d_in, const int* in_sizes, int n_in,
                              void* d_out, int out_size, void* d_ws, size_t ws_size,
                              hipStream_t stream) {
    const float* x    = (const float*)d_in[0];
    const int*   ei   = (const int*)d_in[1];
    const float* ewp  = (const float*)d_in[2];
    const float* W1   = (const float*)d_in[3];
    const float* b1   = (const float*)d_in[4];
    const float* W2   = (const float*)d_in[5];
    const float* b2   = (const float*)d_in[6];
    const float* W3   = (const float*)d_in[7];
    const float* b3   = (const float*)d_in[8];
    const float* Wlin = (const float*)d_in[9];
    const float* blin = (const float*)d_in[10];
    float* out = (float*)d_out;

    const int* src = ei;
    const int* dst = ei + N_EDGES;

    float* ws = (float*)d_ws;
    float* ew     = ws;                                  // E
    float* dinv   = ew + N_EDGES;                        // N
    float* dinv3  = dinv + N_NODES;                      // N
    float* logits = dinv3 + N_NODES;                     // N*8
    int* cnt       = (int*)(logits + (size_t)N_NODES * 8);
    int* cur       = cnt + N_NODES;
    int* row_start = cur + N_NODES;                      // N+1 (block-local)
    int* bsum      = row_start + N_NODES + 1;            // SCAN_BLOCKS
    uint2* ep  = (uint2*)(((uintptr_t)(bsum + SCAN_BLOCKS) + 127) & ~(uintptr_t)127);  // E
    uint2* ep3 = ep + N_EDGES;                           // E
    u16* hb  = (u16*)(ep3 + N_EDGES);                    // M_PAD*256
    u16* x1b = hb  + (size_t)M_PAD * 256;
    u16* x2b = x1b + (size_t)M_PAD * 256;
    u16* x3b = x2b + (size_t)M_PAD * 256;
    u16* wt1 = x3b + (size_t)M_PAD * 256;                // 256*512
    u16* wt2 = wt1 + 256 * 512;
    u16* wt3 = wt2 + 256 * 256;

    dim3 blk(256);
    int nodeBlocks  = (N_NODES + 255) / 256;
    int edgeBlocks  = (N_EDGES + 255) / 256;
    int gathBlocks  = (N_NODES + 3) / 4;
    int rowBlocks32 = (N_NODES + 31) / 32;
    dim3 gemmGrid(M_PAD / 128, 2);

    // prep + CSR
    init_k<<<nodeBlocks, blk, 0, stream>>>(dinv, cnt, cur);
    edge_deg_k<<<edgeBlocks, blk, 0, stream>>>(ewp, dst, dinv, cnt, ew);
    finalize_dinv_k<<<nodeBlocks, blk, 0, stream>>>(dinv, cnt, dinv3);
    scan1_k<<<SCAN_BLOCKS, blk, 0, stream>>>(cnt, row_start, bsum);
    scan2_k<<<1, blk, 0, stream>>>(bsum, row_start);
    fill_k<<<edgeBlocks, blk, 0, stream>>>(src, dst, ew, dinv, dinv3, row_start, bsum,
                                           cur, ep, ep3);

    // weights + pads (merged)
    wtrans_zp_k<<<(WT_TOTAL + ZP_TOTAL + 255) / 256, blk, 0, stream>>>(
        W1, W2, W3, wt1, wt2, wt3, x1b, x2b);

    // ---- layer 1 (A = fp32 x, converted in registers)
    gemm_bf16_k<true><<<gemmGrid, blk, 0, stream>>>(x, wt1, hb, NFEAT);
    gather_k<true><<<gathBlocks, blk, 0, stream>>>(hb, row_start, bsum, ep, dinv, b1, x1b);
    logits_acc_k<0><<<rowBlocks32, blk, 0, stream>>>(x1b, Wlin, blin, logits, nullptr, 0);

    // ---- layer 2
    gemm_bf16_k<false><<<gemmGrid, blk, 0, stream>>>(x1b, wt2, hb, NHID);
    gather_k<true><<<gathBlocks, blk, 0, stream>>>(hb, row_start, bsum, ep, dinv, b2, x2b);
    logits_acc_k<1><<<rowBlocks32, blk, 0, stream>>>(x2b, Wlin, blin, logits, nullptr, 1);

    // ---- layer 3 (ones edge weights) + fused log_softmax in the logits pass
    gemm_bf16_k<false><<<gemmGrid, blk, 0, stream>>>(x2b, wt3, hb, NHID);
    gather_k<false><<<gathBlocks, blk, 0, stream>>>(hb, row_start, bsum, ep3, dinv3, b3, x3b);
    logits_acc_k<2><<<rowBlocks32, blk, 0, stream>>>(x3b, Wlin, blin, logits, out, 2);
}